// Round 1
// baseline (11201.273 us; speedup 1.0000x reference)
//
#include <hip/hip_runtime.h>
#include <math.h>

#define EPSF 1e-7f
#define NPAD 1024
#define KPAD 1024
#define M_PAD 50048   // 391 * 128

typedef __attribute__((ext_vector_type(8))) short bf16x8;
typedef __attribute__((ext_vector_type(4))) float f32x4;

__device__ inline unsigned short f2bf(float f) {
  unsigned u = __float_as_uint(f);
  return (unsigned short)((u + 0x7FFFu + ((u >> 16) & 1u)) >> 16);
}

__device__ inline float block_sum256(float v, float* s4) {
#pragma unroll
  for (int o = 32; o > 0; o >>= 1) v += __shfl_down(v, o);
  int lane = threadIdx.x & 63, w = threadIdx.x >> 6;
  __syncthreads();
  if (lane == 0) s4[w] = v;
  __syncthreads();
  return s4[0] + s4[1] + s4[2] + s4[3];
}

__device__ inline void gload_lds16(const void* g, void* l) {
  __builtin_amdgcn_global_load_lds((const __attribute__((address_space(1))) void*)g,
                                   (__attribute__((address_space(3))) void*)l, 16, 0, 0);
}

// ---------- conversions ----------
__global__ __launch_bounds__(256) void cvt_rows_bf16(const float* __restrict__ x,
                                                     unsigned short* __restrict__ o) {
  int i = blockIdx.x, t = threadIdx.x;
  float4 v = *(const float4*)(x + (size_t)i * 1024 + 4 * t);
  typedef __attribute__((ext_vector_type(4))) unsigned short us4;
  us4 u = {f2bf(v.x), f2bf(v.y), f2bf(v.z), f2bf(v.w)};
  *(us4*)(o + (size_t)i * 1024 + 4 * t) = u;
}

__global__ __launch_bounds__(256) void cvt_w_bf16(const float* __restrict__ W,
                                                  unsigned short* __restrict__ o,
                                                  int rows, int cols) {
  int r = blockIdx.x, t = threadIdx.x;
  int c0 = 4 * t;
  typedef __attribute__((ext_vector_type(4))) unsigned short us4;
  us4 u;
#pragma unroll
  for (int j = 0; j < 4; ++j) {
    int c = c0 + j;
    float v = (r < rows && c < cols) ? W[(size_t)r * cols + c] : 0.0f;
    u[j] = f2bf(v);
  }
  *(us4*)(o + (size_t)r * 1024 + c0) = u;
}

// ---------- GEMM: C[i][j] = sum_k A16[i][k] * B16[j][k] + bias[j] ----------
__global__ __launch_bounds__(256) void gemm_bt(const unsigned short* __restrict__ A,
                                               const unsigned short* __restrict__ B,
                                               const float* __restrict__ bias,
                                               float* __restrict__ C) {
  __shared__ unsigned short lA[128 * 32];
  __shared__ unsigned short lB[128 * 32];
  const int bm = blockIdx.x, bn = blockIdx.y;
  const int tid = threadIdx.x;
  const int wave = tid >> 6, lane = tid & 63;
  const int wr = wave >> 1, wc = wave & 1;
  const int fr = lane & 15, fg = lane >> 4;

  f32x4 acc[4][4];
#pragma unroll
  for (int m = 0; m < 4; ++m)
#pragma unroll
    for (int n2 = 0; n2 < 4; ++n2) acc[m][n2] = (f32x4)0.0f;

  for (int k0 = 0; k0 < KPAD; k0 += 32) {
    // stage: linear LDS dest (base + lane*16), inverse-swizzled global k (G21)
#pragma unroll
    for (int q = 0; q < 2; ++q) {
      int row = q * 64 + wave * 16 + (lane >> 2);
      int kk = ((lane & 3) ^ ((row >> 1) & 3)) << 3;
      gload_lds16(A + (size_t)(bm * 128 + row) * KPAD + k0 + kk,
                  &lA[row * 32 + ((lane & 3) << 3)]);
      gload_lds16(B + (size_t)(bn * 128 + row) * KPAD + k0 + kk,
                  &lB[row * 32 + ((lane & 3) << 3)]);
    }
    __syncthreads();
    bf16x8 a[4], b[4];
#pragma unroll
    for (int m = 0; m < 4; ++m) {
      int row = wr * 64 + m * 16 + fr;
      a[m] = *(const bf16x8*)&lA[row * 32 + ((fg ^ ((row >> 1) & 3)) << 3)];
    }
#pragma unroll
    for (int n2 = 0; n2 < 4; ++n2) {
      int row = wc * 64 + n2 * 16 + fr;
      b[n2] = *(const bf16x8*)&lB[row * 32 + ((fg ^ ((row >> 1) & 3)) << 3)];
    }
#pragma unroll
    for (int m = 0; m < 4; ++m)
#pragma unroll
      for (int n2 = 0; n2 < 4; ++n2)
        acc[m][n2] = __builtin_amdgcn_mfma_f32_16x16x32_bf16(a[m], b[n2], acc[m][n2], 0, 0, 0);
    __syncthreads();
  }

  const int crow0 = bm * 128 + wr * 64;
  const int ccol0 = bn * 128 + wc * 64;
#pragma unroll
  for (int m = 0; m < 4; ++m) {
#pragma unroll
    for (int n2 = 0; n2 < 4; ++n2) {
      int col = ccol0 + n2 * 16 + fr;
      float bv = (col < 1023) ? bias[col] : 0.0f;
      int row0 = crow0 + m * 16 + fg * 4;
      float* cp = C + (size_t)row0 * NPAD + col;
#pragma unroll
      for (int j = 0; j < 4; ++j) cp[(size_t)j * NPAD] = acc[m][n2][j] + bv;
    }
  }
}

// ---------- rowwise expmap0 (in place over mx). layout: spatial[0..1022], time@1023
__global__ __launch_bounds__(256) void expmap_rows(float* __restrict__ mxh, float sqrtK) {
  __shared__ float s4[4];
  int i = blockIdx.x, t = threadIdx.x;
  float* r = mxh + (size_t)i * 1024 + 4 * t;
  float4 v = *(const float4*)r;
  if (t == 255) v.w = 0.0f;  // col 1023 is pad
  float ss = block_sum256(v.x * v.x + v.y * v.y + v.z * v.z + v.w * v.w, s4);
  float un = fmaxf(sqrtf(ss), EPSF);
  float tt = un / sqrtK;
  float e = expf(tt);
  float ch = 0.5f * (e + 1.0f / e), sh = 0.5f * (e - 1.0f / e);
  float h0 = sqrtK * ch, sc = sqrtK * sh / un;
  float4 o;
  o.x = sc * v.x; o.y = sc * v.y; o.z = sc * v.z;
  o.w = (t == 255) ? h0 : sc * v.w;
  *(float4*)r = o;
}

// ---------- edge scatter: m[dst] += w * h[src] ----------
__global__ __launch_bounds__(256) void scatter_edges(const float* __restrict__ h,
                                                     const int* __restrict__ es,
                                                     const int* __restrict__ ed,
                                                     const float* __restrict__ ew,
                                                     float* __restrict__ m) {
  int e = blockIdx.x;
  int src = es[e], dst = ed[e];
  float w = ew[e];
  int t = threadIdx.x;
  float4 v = *(const float4*)(h + (size_t)src * 1024 + 4 * t);
  float* mp = m + (size_t)dst * 1024 + 4 * t;
  atomicAdd(mp + 0, w * v.x);
  atomicAdd(mp + 1, w * v.y);
  atomicAdd(mp + 2, w * v.z);
  atomicAdd(mp + 3, w * v.w);
}

// ---------- centroid + logmap0 + relu -> bf16 tangent (layer-1 tail) ----------
__global__ __launch_bounds__(256) void centroid_tangent_bf16(const float* __restrict__ m,
                                                             unsigned short* __restrict__ u16,
                                                             float sqrtK) {
  __shared__ float s4[4];
  int i = blockIdx.x, t = threadIdx.x;
  const float* r = m + (size_t)i * 1024;
  float4 v = *(const float4*)(r + 4 * t);
  float m0 = r[1023];
  if (t == 255) v.w = 0.0f;
  float ss = block_sum256(v.x * v.x + v.y * v.y + v.z * v.z + v.w * v.w, s4);
  float l = ss - m0 * m0;
  float denom = sqrtf(fmaxf(fabsf(l), EPSF));
  float c = sqrtK / denom;
  float xn = fmaxf(c * sqrtf(ss), EPSF);
  float theta = fmaxf(m0 / denom, 1.0f + EPSF);
  float d = sqrtK * acoshf(theta);
  float f = c * (d / xn);
  typedef __attribute__((ext_vector_type(4))) unsigned short us4;
  us4 u;
  u[0] = f2bf(fmaxf(v.x, 0.0f) * f);
  u[1] = f2bf(fmaxf(v.y, 0.0f) * f);
  u[2] = f2bf(fmaxf(v.z, 0.0f) * f);
  u[3] = (t == 255) ? (unsigned short)0 : f2bf(fmaxf(v.w, 0.0f) * f);
  *(us4*)(u16 + (size_t)i * 1024 + 4 * t) = u;
}

// ---------- centroid + logmap0 + relu + expmap0 + proj -> y (layer-2 tail) ----------
__global__ __launch_bounds__(256) void centroid_final(const float* __restrict__ m,
                                                      float* __restrict__ y,
                                                      float sqrtKin, float sqrtKout) {
  __shared__ float s4[4];
  int i = blockIdx.x, t = threadIdx.x;
  const float* r = m + (size_t)i * 1024;
  float4 v = *(const float4*)(r + 4 * t);
  float m0 = r[1023];
  if (t == 255) v.w = 0.0f;
  float ss = block_sum256(v.x * v.x + v.y * v.y + v.z * v.z + v.w * v.w, s4);
  float l = ss - m0 * m0;
  float denom = sqrtf(fmaxf(fabsf(l), EPSF));
  float c = sqrtKin / denom;
  float xn = fmaxf(c * sqrtf(ss), EPSF);
  float theta = fmaxf(m0 / denom, 1.0f + EPSF);
  float d = sqrtKin * acoshf(theta);
  float f = c * (d / xn);
  float4 o;
  o.x = fmaxf(v.x, 0.0f) * f;
  o.y = fmaxf(v.y, 0.0f) * f;
  o.z = fmaxf(v.z, 0.0f) * f;
  o.w = (t == 255) ? 0.0f : fmaxf(v.w, 0.0f) * f;
  float ss2 = block_sum256(o.x * o.x + o.y * o.y + o.z * o.z + o.w * o.w, s4);
  float un = fmaxf(sqrtf(ss2), EPSF);
  float tt = un / sqrtKout;
  float e = expf(tt);
  float ch = 0.5f * (e + 1.0f / e), sh = 0.5f * (e - 1.0f / e);
  float y0 = sqrtKout * ch, sc = sqrtKout * sh / un;
  float* yr = y + (size_t)i * 1024;
  int c0 = 4 * t;
  yr[1 + c0] = sc * o.x;
  yr[2 + c0] = sc * o.y;
  yr[3 + c0] = sc * o.z;
  if (c0 + 3 < 1023) yr[4 + c0] = sc * o.w;
  if (t == 0) yr[0] = y0;
}

extern "C" void kernel_launch(void* const* d_in, const int* in_sizes, int n_in,
                              void* d_out, int out_size, void* d_ws, size_t ws_size,
                              hipStream_t stream) {
  const float* x = (const float*)d_in[0];
  const int* es = (const int*)d_in[1];
  const int* ed = (const int*)d_in[2];
  const float* ew = (const float*)d_in[3];
  const float* W1 = (const float*)d_in[4];
  const float* b1 = (const float*)d_in[5];
  const float* W2 = (const float*)d_in[6];
  const float* b2 = (const float*)d_in[7];
  float* y = (float*)d_out;

  const int n = in_sizes[0] / 1024;  // 50000
  const int nE = in_sizes[1];        // 400000

  // workspace layout (all offsets 256B-aligned)
  const size_t sz_u16 = (size_t)M_PAD * 1024 * 2;  // 102,498,304
  const size_t sz_w16 = (size_t)1024 * 1024 * 2;   //   2,097,152
  const size_t sz_mx = (size_t)M_PAD * 1024 * 4;   // 204,996,608
  char* ws = (char*)d_ws;
  unsigned short* u16 = (unsigned short*)ws;
  unsigned short* w16 = (unsigned short*)(ws + sz_u16);
  float* mx = (float*)(ws + sz_u16 + sz_w16);
  float* mbuf = (float*)(ws + sz_u16 + sz_w16 + sz_mx);

  const float sK1 = 1.0f;                 // sqrt(K_IN)
  const float sK2 = 1.0488088481701516f;  // sqrt(1.1)
  const float sK3 = 1.0954451150103321f;  // sqrt(1.2)

  dim3 ggrid(391, 8);

  // ----- layer 1 -----
  cvt_rows_bf16<<<n, 256, 0, stream>>>(x, u16);
  cvt_w_bf16<<<1024, 256, 0, stream>>>(W1, w16, 1023, 1024);
  gemm_bt<<<ggrid, 256, 0, stream>>>(u16, w16, b1, mx);
  expmap_rows<<<n, 256, 0, stream>>>(mx, sK1);
  hipMemsetAsync(mbuf, 0, (size_t)n * 1024 * 4, stream);
  scatter_edges<<<nE, 256, 0, stream>>>(mx, es, ed, ew, mbuf);
  centroid_tangent_bf16<<<n, 256, 0, stream>>>(mbuf, u16, sK1);

  // ----- layer 2 -----
  cvt_w_bf16<<<1024, 256, 0, stream>>>(W2, w16, 1023, 1023);
  gemm_bt<<<ggrid, 256, 0, stream>>>(u16, w16, b2, mx);
  expmap_rows<<<n, 256, 0, stream>>>(mx, sK2);
  hipMemsetAsync(mbuf, 0, (size_t)n * 1024 * 4, stream);
  scatter_edges<<<nE, 256, 0, stream>>>(mx, es, ed, ew, mbuf);
  centroid_final<<<n, 256, 0, stream>>>(mbuf, y, sK2, sK3);
}

// Round 2
// 1066.620 us; speedup vs baseline: 10.5017x; 10.5017x over previous
//
#include <hip/hip_runtime.h>
#include <math.h>

#define EPSF 1e-7f
#define NPAD 1024
#define KPAD 1024
#define M_PAD 50048   // 391 * 128

typedef __attribute__((ext_vector_type(8))) short bf16x8;
typedef __attribute__((ext_vector_type(4))) float f32x4;

__device__ inline unsigned short f2bf(float f) {
  unsigned u = __float_as_uint(f);
  return (unsigned short)((u + 0x7FFFu + ((u >> 16) & 1u)) >> 16);
}

__device__ inline float block_sum256(float v, float* s4) {
#pragma unroll
  for (int o = 32; o > 0; o >>= 1) v += __shfl_down(v, o);
  int lane = threadIdx.x & 63, w = threadIdx.x >> 6;
  __syncthreads();
  if (lane == 0) s4[w] = v;
  __syncthreads();
  return s4[0] + s4[1] + s4[2] + s4[3];
}

__device__ inline void gload_lds16(const void* g, void* l) {
  __builtin_amdgcn_global_load_lds((const __attribute__((address_space(1))) void*)g,
                                   (__attribute__((address_space(3))) void*)l, 16, 0, 0);
}

// ---------- conversions ----------
__global__ __launch_bounds__(256) void cvt_rows_bf16(const float* __restrict__ x,
                                                     unsigned short* __restrict__ o) {
  int i = blockIdx.x, t = threadIdx.x;
  float4 v = *(const float4*)(x + (size_t)i * 1024 + 4 * t);
  typedef __attribute__((ext_vector_type(4))) unsigned short us4;
  us4 u = {f2bf(v.x), f2bf(v.y), f2bf(v.z), f2bf(v.w)};
  *(us4*)(o + (size_t)i * 1024 + 4 * t) = u;
}

__global__ __launch_bounds__(256) void cvt_w_bf16(const float* __restrict__ W,
                                                  unsigned short* __restrict__ o,
                                                  int rows, int cols) {
  int r = blockIdx.x, t = threadIdx.x;
  int c0 = 4 * t;
  typedef __attribute__((ext_vector_type(4))) unsigned short us4;
  us4 u;
#pragma unroll
  for (int j = 0; j < 4; ++j) {
    int c = c0 + j;
    float v = (r < rows && c < cols) ? W[(size_t)r * cols + c] : 0.0f;
    u[j] = f2bf(v);
  }
  *(us4*)(o + (size_t)r * 1024 + c0) = u;
}

// ---------- GEMM: C[i][j] = sum_k A16[i][k] * B16[j][k] + bias[j] ----------
__global__ __launch_bounds__(256) void gemm_bt(const unsigned short* __restrict__ A,
                                               const unsigned short* __restrict__ B,
                                               const float* __restrict__ bias,
                                               float* __restrict__ C) {
  __shared__ unsigned short lA[128 * 32];
  __shared__ unsigned short lB[128 * 32];
  const int bm = blockIdx.x, bn = blockIdx.y;
  const int tid = threadIdx.x;
  const int wave = tid >> 6, lane = tid & 63;
  const int wr = wave >> 1, wc = wave & 1;
  const int fr = lane & 15, fg = lane >> 4;

  f32x4 acc[4][4];
#pragma unroll
  for (int m = 0; m < 4; ++m)
#pragma unroll
    for (int n2 = 0; n2 < 4; ++n2) acc[m][n2] = (f32x4)0.0f;

  for (int k0 = 0; k0 < KPAD; k0 += 32) {
#pragma unroll
    for (int q = 0; q < 2; ++q) {
      int row = q * 64 + wave * 16 + (lane >> 2);
      int kk = ((lane & 3) ^ ((row >> 1) & 3)) << 3;
      gload_lds16(A + (size_t)(bm * 128 + row) * KPAD + k0 + kk,
                  &lA[row * 32 + ((lane & 3) << 3)]);
      gload_lds16(B + (size_t)(bn * 128 + row) * KPAD + k0 + kk,
                  &lB[row * 32 + ((lane & 3) << 3)]);
    }
    __syncthreads();
    bf16x8 a[4], b[4];
#pragma unroll
    for (int m = 0; m < 4; ++m) {
      int row = wr * 64 + m * 16 + fr;
      a[m] = *(const bf16x8*)&lA[row * 32 + ((fg ^ ((row >> 1) & 3)) << 3)];
    }
#pragma unroll
    for (int n2 = 0; n2 < 4; ++n2) {
      int row = wc * 64 + n2 * 16 + fr;
      b[n2] = *(const bf16x8*)&lB[row * 32 + ((fg ^ ((row >> 1) & 3)) << 3)];
    }
#pragma unroll
    for (int m = 0; m < 4; ++m)
#pragma unroll
      for (int n2 = 0; n2 < 4; ++n2)
        acc[m][n2] = __builtin_amdgcn_mfma_f32_16x16x32_bf16(a[m], b[n2], acc[m][n2], 0, 0, 0);
    __syncthreads();
  }

  const int crow0 = bm * 128 + wr * 64;
  const int ccol0 = bn * 128 + wc * 64;
#pragma unroll
  for (int m = 0; m < 4; ++m) {
#pragma unroll
    for (int n2 = 0; n2 < 4; ++n2) {
      int col = ccol0 + n2 * 16 + fr;
      float bv = (col < 1023) ? bias[col] : 0.0f;
      int row0 = crow0 + m * 16 + fg * 4;
      float* cp = C + (size_t)row0 * NPAD + col;
#pragma unroll
      for (int j = 0; j < 4; ++j) cp[(size_t)j * NPAD] = acc[m][n2][j] + bv;
    }
  }
}

// ---------- rowwise expmap0 (in place over mx). layout: spatial[0..1022], time@1023
__global__ __launch_bounds__(256) void expmap_rows(float* __restrict__ mxh, float sqrtK) {
  __shared__ float s4[4];
  int i = blockIdx.x, t = threadIdx.x;
  float* r = mxh + (size_t)i * 1024 + 4 * t;
  float4 v = *(const float4*)r;
  if (t == 255) v.w = 0.0f;  // col 1023 is pad
  float ss = block_sum256(v.x * v.x + v.y * v.y + v.z * v.z + v.w * v.w, s4);
  float un = fmaxf(sqrtf(ss), EPSF);
  float tt = un / sqrtK;
  float e = expf(tt);
  float ch = 0.5f * (e + 1.0f / e), sh = 0.5f * (e - 1.0f / e);
  float h0 = sqrtK * ch, sc = sqrtK * sh / un;
  float4 o;
  o.x = sc * v.x; o.y = sc * v.y; o.z = sc * v.z;
  o.w = (t == 255) ? h0 : sc * v.w;
  *(float4*)r = o;
}

// ---------- CSR build ----------
__global__ __launch_bounds__(256) void deg_count(const int* __restrict__ ed, int* __restrict__ cnt,
                                                 int nE) {
  int i = blockIdx.x * 256 + threadIdx.x;
  if (i < nE) atomicAdd(&cnt[ed[i]], 1);
}

__global__ __launch_bounds__(256) void scan1(const int* __restrict__ cnt, int* __restrict__ excl,
                                             int* __restrict__ bsum, int n) {
  __shared__ int s[256];
  int t = threadIdx.x;
  int i = blockIdx.x * 256 + t;
  int v = (i < n) ? cnt[i] : 0;
  s[t] = v;
  __syncthreads();
#pragma unroll
  for (int o = 1; o < 256; o <<= 1) {
    int add = (t >= o) ? s[t - o] : 0;
    __syncthreads();
    s[t] += add;
    __syncthreads();
  }
  if (i < n) excl[i] = s[t] - v;
  if (t == 255) bsum[blockIdx.x] = s[t];
}

__global__ __launch_bounds__(256) void scan2(int* __restrict__ bsum, int* __restrict__ boff,
                                             int nb) {
  __shared__ int s[256];
  int t = threadIdx.x;
  int v = (t < nb) ? bsum[t] : 0;
  s[t] = v;
  __syncthreads();
#pragma unroll
  for (int o = 1; o < 256; o <<= 1) {
    int add = (t >= o) ? s[t - o] : 0;
    __syncthreads();
    s[t] += add;
    __syncthreads();
  }
  if (t < nb) boff[t] = s[t] - v;
}

__global__ __launch_bounds__(256) void scan3(int* __restrict__ excl, const int* __restrict__ boff,
                                             int* __restrict__ rowstart, int* __restrict__ fill,
                                             int n, int nE) {
  int i = blockIdx.x * 256 + threadIdx.x;
  if (i < n) {
    int v = excl[i] + boff[blockIdx.x];
    rowstart[i] = v;
    fill[i] = v;
  }
  if (i == 0) rowstart[n] = nE;
}

__global__ __launch_bounds__(256) void bucket_fill(const int* __restrict__ es,
                                                   const int* __restrict__ ed,
                                                   const float* __restrict__ ew,
                                                   int* __restrict__ fill,
                                                   int2* __restrict__ sedge, int nE) {
  int i = blockIdx.x * 256 + threadIdx.x;
  if (i < nE) {
    int d = ed[i];
    int pos = atomicAdd(&fill[d], 1);
    sedge[pos] = make_int2(es[i], __float_as_int(ew[i]));
  }
}

// ---------- gather + centroid + logmap0 + relu -> bf16 tangent (layer-1 tail) ----------
__global__ __launch_bounds__(256) void gather_centroid_tangent(
    const float* __restrict__ h, const int* __restrict__ rs, const int2* __restrict__ sedge,
    unsigned short* __restrict__ u16, float sqrtK) {
  __shared__ float s4[4];
  __shared__ float sm0;
  int i = blockIdx.x, t = threadIdx.x;
  int j0 = rs[i], j1 = rs[i + 1];
  float4 acc = make_float4(0.f, 0.f, 0.f, 0.f);
  for (int j = j0; j < j1; ++j) {
    int2 e = sedge[j];
    float w = __int_as_float(e.y);
    float4 v = *(const float4*)(h + (size_t)e.x * 1024 + 4 * t);
    acc.x += w * v.x; acc.y += w * v.y; acc.z += w * v.z; acc.w += w * v.w;
  }
  if (t == 255) sm0 = acc.w;
  __syncthreads();
  float m0 = sm0;
  if (t == 255) acc.w = 0.0f;
  float ss = block_sum256(acc.x * acc.x + acc.y * acc.y + acc.z * acc.z + acc.w * acc.w, s4);
  float l = ss - m0 * m0;
  float denom = sqrtf(fmaxf(fabsf(l), EPSF));
  float c = sqrtK / denom;
  float xn = fmaxf(c * sqrtf(ss), EPSF);
  float theta = fmaxf(m0 / denom, 1.0f + EPSF);
  float d = sqrtK * acoshf(theta);
  float f = c * (d / xn);
  typedef __attribute__((ext_vector_type(4))) unsigned short us4;
  us4 u;
  u[0] = f2bf(fmaxf(acc.x, 0.0f) * f);
  u[1] = f2bf(fmaxf(acc.y, 0.0f) * f);
  u[2] = f2bf(fmaxf(acc.z, 0.0f) * f);
  u[3] = (t == 255) ? (unsigned short)0 : f2bf(fmaxf(acc.w, 0.0f) * f);
  *(us4*)(u16 + (size_t)i * 1024 + 4 * t) = u;
}

// ---------- gather + centroid + logmap0 + relu + expmap0 + proj -> y (layer-2 tail) ----------
__global__ __launch_bounds__(256) void gather_centroid_final(
    const float* __restrict__ h, const int* __restrict__ rs, const int2* __restrict__ sedge,
    float* __restrict__ y, float sqrtKin, float sqrtKout) {
  __shared__ float s4[4];
  __shared__ float sm0;
  int i = blockIdx.x, t = threadIdx.x;
  int j0 = rs[i], j1 = rs[i + 1];
  float4 acc = make_float4(0.f, 0.f, 0.f, 0.f);
  for (int j = j0; j < j1; ++j) {
    int2 e = sedge[j];
    float w = __int_as_float(e.y);
    float4 v = *(const float4*)(h + (size_t)e.x * 1024 + 4 * t);
    acc.x += w * v.x; acc.y += w * v.y; acc.z += w * v.z; acc.w += w * v.w;
  }
  if (t == 255) sm0 = acc.w;
  __syncthreads();
  float m0 = sm0;
  if (t == 255) acc.w = 0.0f;
  float ss = block_sum256(acc.x * acc.x + acc.y * acc.y + acc.z * acc.z + acc.w * acc.w, s4);
  float l = ss - m0 * m0;
  float denom = sqrtf(fmaxf(fabsf(l), EPSF));
  float c = sqrtKin / denom;
  float xn = fmaxf(c * sqrtf(ss), EPSF);
  float theta = fmaxf(m0 / denom, 1.0f + EPSF);
  float d = sqrtKin * acoshf(theta);
  float f = c * (d / xn);
  float4 o;
  o.x = fmaxf(acc.x, 0.0f) * f;
  o.y = fmaxf(acc.y, 0.0f) * f;
  o.z = fmaxf(acc.z, 0.0f) * f;
  o.w = (t == 255) ? 0.0f : fmaxf(acc.w, 0.0f) * f;
  float ss2 = block_sum256(o.x * o.x + o.y * o.y + o.z * o.z + o.w * o.w, s4);
  float un = fmaxf(sqrtf(ss2), EPSF);
  float tt = un / sqrtKout;
  float e = expf(tt);
  float ch = 0.5f * (e + 1.0f / e), sh = 0.5f * (e - 1.0f / e);
  float y0 = sqrtKout * ch, sc = sqrtKout * sh / un;
  float* yr = y + (size_t)i * 1024;
  int c0 = 4 * t;
  yr[1 + c0] = sc * o.x;
  yr[2 + c0] = sc * o.y;
  yr[3 + c0] = sc * o.z;
  if (c0 + 3 < 1023) yr[4 + c0] = sc * o.w;
  if (t == 0) yr[0] = y0;
}

extern "C" void kernel_launch(void* const* d_in, const int* in_sizes, int n_in,
                              void* d_out, int out_size, void* d_ws, size_t ws_size,
                              hipStream_t stream) {
  const float* x = (const float*)d_in[0];
  const int* es = (const int*)d_in[1];
  const int* ed = (const int*)d_in[2];
  const float* ew = (const float*)d_in[3];
  const float* W1 = (const float*)d_in[4];
  const float* b1 = (const float*)d_in[5];
  const float* W2 = (const float*)d_in[6];
  const float* b2 = (const float*)d_in[7];
  float* y = (float*)d_out;

  const int n = in_sizes[0] / 1024;  // 50000
  const int nE = in_sizes[1];        // 400000
  const int NB = (n + 255) / 256;    // 196
  const int EB = (nE + 255) / 256;

  // workspace layout (offsets 256B-aligned)
  char* ws = (char*)d_ws;
  size_t off = 0;
  auto alloc = [&](size_t bytes) {
    void* p = ws + off;
    off += (bytes + 255) & ~(size_t)255;
    return p;
  };
  unsigned short* u16 = (unsigned short*)alloc((size_t)M_PAD * 1024 * 2);
  unsigned short* w16 = (unsigned short*)alloc((size_t)1024 * 1024 * 2);
  float* mx = (float*)alloc((size_t)M_PAD * 1024 * 4);
  int* cnt = (int*)alloc((size_t)(n + 1) * 4);
  int* excl = (int*)alloc((size_t)n * 4);
  int* rowstart = (int*)alloc((size_t)(n + 1) * 4);
  int* fill = (int*)alloc((size_t)n * 4);
  int* bsum = (int*)alloc(256 * 4);
  int* boff = (int*)alloc(256 * 4);
  int2* sedge = (int2*)alloc((size_t)nE * 8);

  const float sK1 = 1.0f;                 // sqrt(K_IN)
  const float sK2 = 1.0488088481701516f;  // sqrt(1.1)
  const float sK3 = 1.0954451150103321f;  // sqrt(1.2)

  dim3 ggrid(391, 8);

  // ----- CSR build (edges shared by both layers) -----
  hipMemsetAsync(cnt, 0, (size_t)(n + 1) * 4, stream);
  deg_count<<<EB, 256, 0, stream>>>(ed, cnt, nE);
  scan1<<<NB, 256, 0, stream>>>(cnt, excl, bsum, n);
  scan2<<<1, 256, 0, stream>>>(bsum, boff, NB);
  scan3<<<NB, 256, 0, stream>>>(excl, boff, rowstart, fill, n, nE);
  bucket_fill<<<EB, 256, 0, stream>>>(es, ed, ew, fill, sedge, nE);

  // ----- layer 1 -----
  cvt_rows_bf16<<<n, 256, 0, stream>>>(x, u16);
  cvt_w_bf16<<<1024, 256, 0, stream>>>(W1, w16, 1023, 1024);
  gemm_bt<<<ggrid, 256, 0, stream>>>(u16, w16, b1, mx);
  expmap_rows<<<n, 256, 0, stream>>>(mx, sK1);
  gather_centroid_tangent<<<n, 256, 0, stream>>>(mx, rowstart, sedge, u16, sK1);

  // ----- layer 2 -----
  cvt_w_bf16<<<1024, 256, 0, stream>>>(W2, w16, 1023, 1023);
  gemm_bt<<<ggrid, 256, 0, stream>>>(u16, w16, b2, mx);
  expmap_rows<<<n, 256, 0, stream>>>(mx, sK2);
  gather_centroid_final<<<n, 256, 0, stream>>>(mx, rowstart, sedge, y, sK2, sK3);
}

// Round 3
// 878.765 us; speedup vs baseline: 12.7466x; 1.2138x over previous
//
#include <hip/hip_runtime.h>
#include <math.h>

#define EPSF 1e-7f
#define NPAD 1024
#define KPAD 1024
#define M_PAD 50048   // 391 * 128

typedef __attribute__((ext_vector_type(8))) short bf16x8;
typedef __attribute__((ext_vector_type(4))) float f32x4;
typedef __attribute__((ext_vector_type(4))) unsigned short us4;
typedef __attribute__((ext_vector_type(8))) unsigned short us8;

__device__ inline unsigned short f2bf(float f) {
  unsigned u = __float_as_uint(f);
  return (unsigned short)((u + 0x7FFFu + ((u >> 16) & 1u)) >> 16);
}
__device__ inline float bf2f(unsigned short s) {
  return __uint_as_float(((unsigned)s) << 16);
}

__device__ inline float block_sum256(float v, float* s4) {
#pragma unroll
  for (int o = 32; o > 0; o >>= 1) v += __shfl_down(v, o);
  int lane = threadIdx.x & 63, w = threadIdx.x >> 6;
  __syncthreads();
  if (lane == 0) s4[w] = v;
  __syncthreads();
  return s4[0] + s4[1] + s4[2] + s4[3];
}

__device__ inline void gload_lds16(const void* g, void* l) {
  __builtin_amdgcn_global_load_lds((const __attribute__((address_space(1))) void*)g,
                                   (__attribute__((address_space(3))) void*)l, 16, 0, 0);
}

// ---------- conversions ----------
__global__ __launch_bounds__(256) void cvt_rows_bf16(const float* __restrict__ x,
                                                     unsigned short* __restrict__ o) {
  int i = blockIdx.x, t = threadIdx.x;
  float4 v = *(const float4*)(x + (size_t)i * 1024 + 4 * t);
  us4 u = {f2bf(v.x), f2bf(v.y), f2bf(v.z), f2bf(v.w)};
  *(us4*)(o + (size_t)i * 1024 + 4 * t) = u;
}

__global__ __launch_bounds__(256) void cvt_w_bf16(const float* __restrict__ W,
                                                  unsigned short* __restrict__ o,
                                                  int rows, int cols) {
  int r = blockIdx.x, t = threadIdx.x;
  int c0 = 4 * t;
  us4 u;
#pragma unroll
  for (int j = 0; j < 4; ++j) {
    int c = c0 + j;
    float v = (r < rows && c < cols) ? W[(size_t)r * cols + c] : 0.0f;
    u[j] = f2bf(v);
  }
  *(us4*)(o + (size_t)r * 1024 + c0) = u;
}

// ---------- GEMM: C[i][j] = sum_k A16[i][k] * B16[j][k] + bias[j] ----------
__global__ __launch_bounds__(256) void gemm_bt(const unsigned short* __restrict__ A,
                                               const unsigned short* __restrict__ B,
                                               const float* __restrict__ bias,
                                               float* __restrict__ C) {
  __shared__ unsigned short lA[128 * 32];
  __shared__ unsigned short lB[128 * 32];
  const int bm = blockIdx.x, bn = blockIdx.y;
  const int tid = threadIdx.x;
  const int wave = tid >> 6, lane = tid & 63;
  const int wr = wave >> 1, wc = wave & 1;
  const int fr = lane & 15, fg = lane >> 4;

  f32x4 acc[4][4];
#pragma unroll
  for (int m = 0; m < 4; ++m)
#pragma unroll
    for (int n2 = 0; n2 < 4; ++n2) acc[m][n2] = (f32x4)0.0f;

  for (int k0 = 0; k0 < KPAD; k0 += 32) {
#pragma unroll
    for (int q = 0; q < 2; ++q) {
      int row = q * 64 + wave * 16 + (lane >> 2);
      int kk = ((lane & 3) ^ ((row >> 1) & 3)) << 3;
      gload_lds16(A + (size_t)(bm * 128 + row) * KPAD + k0 + kk,
                  &lA[row * 32 + ((lane & 3) << 3)]);
      gload_lds16(B + (size_t)(bn * 128 + row) * KPAD + k0 + kk,
                  &lB[row * 32 + ((lane & 3) << 3)]);
    }
    __syncthreads();
    bf16x8 a[4], b[4];
#pragma unroll
    for (int m = 0; m < 4; ++m) {
      int row = wr * 64 + m * 16 + fr;
      a[m] = *(const bf16x8*)&lA[row * 32 + ((fg ^ ((row >> 1) & 3)) << 3)];
    }
#pragma unroll
    for (int n2 = 0; n2 < 4; ++n2) {
      int row = wc * 64 + n2 * 16 + fr;
      b[n2] = *(const bf16x8*)&lB[row * 32 + ((fg ^ ((row >> 1) & 3)) << 3)];
    }
#pragma unroll
    for (int m = 0; m < 4; ++m)
#pragma unroll
      for (int n2 = 0; n2 < 4; ++n2)
        acc[m][n2] = __builtin_amdgcn_mfma_f32_16x16x32_bf16(a[m], b[n2], acc[m][n2], 0, 0, 0);
    __syncthreads();
  }

  const int crow0 = bm * 128 + wr * 64;
  const int ccol0 = bn * 128 + wc * 64;
#pragma unroll
  for (int m = 0; m < 4; ++m) {
#pragma unroll
    for (int n2 = 0; n2 < 4; ++n2) {
      int col = ccol0 + n2 * 16 + fr;
      float bv = (col < 1023) ? bias[col] : 0.0f;
      int row0 = crow0 + m * 16 + fg * 4;
      float* cp = C + (size_t)row0 * NPAD + col;
#pragma unroll
      for (int j = 0; j < 4; ++j) cp[(size_t)j * NPAD] = acc[m][n2][j] + bv;
    }
  }
}

// ---------- rowwise expmap0: mx (fp32) -> h (bf16), time coord baked at col 1023
__global__ __launch_bounds__(256) void expmap_to_bf16(const float* __restrict__ mx,
                                                      unsigned short* __restrict__ h,
                                                      float sqrtK) {
  __shared__ float s4[4];
  int i = blockIdx.x, t = threadIdx.x;
  const float* r = mx + (size_t)i * 1024 + 4 * t;
  float4 v = *(const float4*)r;
  if (t == 255) v.w = 0.0f;  // col 1023 is pad
  float ss = block_sum256(v.x * v.x + v.y * v.y + v.z * v.z + v.w * v.w, s4);
  float un = fmaxf(sqrtf(ss), EPSF);
  float tt = un / sqrtK;
  float e = expf(tt);
  float ch = 0.5f * (e + 1.0f / e), sh = 0.5f * (e - 1.0f / e);
  float h0 = sqrtK * ch, sc = sqrtK * sh / un;
  us4 u;
  u[0] = f2bf(sc * v.x);
  u[1] = f2bf(sc * v.y);
  u[2] = f2bf(sc * v.z);
  u[3] = (t == 255) ? f2bf(h0) : f2bf(sc * v.w);
  *(us4*)(h + (size_t)i * 1024 + 4 * t) = u;
}

// ---------- CSR build ----------
__global__ __launch_bounds__(256) void deg_count(const int* __restrict__ ed, int* __restrict__ cnt,
                                                 int nE) {
  int i = blockIdx.x * 256 + threadIdx.x;
  if (i < nE) atomicAdd(&cnt[ed[i]], 1);
}

__global__ __launch_bounds__(256) void scan1(const int* __restrict__ cnt, int* __restrict__ excl,
                                             int* __restrict__ bsum, int n) {
  __shared__ int s[256];
  int t = threadIdx.x;
  int i = blockIdx.x * 256 + t;
  int v = (i < n) ? cnt[i] : 0;
  s[t] = v;
  __syncthreads();
#pragma unroll
  for (int o = 1; o < 256; o <<= 1) {
    int add = (t >= o) ? s[t - o] : 0;
    __syncthreads();
    s[t] += add;
    __syncthreads();
  }
  if (i < n) excl[i] = s[t] - v;
  if (t == 255) bsum[blockIdx.x] = s[t];
}

__global__ __launch_bounds__(256) void scan2(int* __restrict__ bsum, int* __restrict__ boff,
                                             int nb) {
  __shared__ int s[256];
  int t = threadIdx.x;
  int v = (t < nb) ? bsum[t] : 0;
  s[t] = v;
  __syncthreads();
#pragma unroll
  for (int o = 1; o < 256; o <<= 1) {
    int add = (t >= o) ? s[t - o] : 0;
    __syncthreads();
    s[t] += add;
    __syncthreads();
  }
  if (t < nb) boff[t] = s[t] - v;
}

__global__ __launch_bounds__(256) void scan3(int* __restrict__ excl, const int* __restrict__ boff,
                                             int* __restrict__ rowstart, int* __restrict__ fill,
                                             int n, int nE) {
  int i = blockIdx.x * 256 + threadIdx.x;
  if (i < n) {
    int v = excl[i] + boff[blockIdx.x];
    rowstart[i] = v;
    fill[i] = v;
  }
  if (i == 0) rowstart[n] = nE;
}

__global__ __launch_bounds__(256) void bucket_fill(const int* __restrict__ es,
                                                   const int* __restrict__ ed,
                                                   const float* __restrict__ ew,
                                                   int* __restrict__ fill,
                                                   int2* __restrict__ sedge, int nE) {
  int i = blockIdx.x * 256 + threadIdx.x;
  if (i < nE) {
    int d = ed[i];
    int pos = atomicAdd(&fill[d], 1);
    sedge[pos] = make_int2(es[i], __float_as_int(ew[i]));
  }
}

// ---------- gather (bf16 h, 2 dst rows / block, 8 cols / thread) + centroid+logmap+relu ----------
// -> bf16 tangent (layer-1 tail)
__global__ __launch_bounds__(256) void gather_centroid_tangent(
    const unsigned short* __restrict__ h, const int* __restrict__ rs,
    const int2* __restrict__ sedge, unsigned short* __restrict__ u16, float sqrtK, int n) {
  __shared__ float s4[4];
  __shared__ float sm0[2];
  int g = threadIdx.x >> 7;   // sub-block 0/1
  int t = threadIdx.x & 127;  // 0..127
  int i = blockIdx.x * 2 + g;
  bool alive = (i < n);
  int j0 = alive ? rs[i] : 0, j1 = alive ? rs[i + 1] : 0;
  float acc[8] = {0.f, 0.f, 0.f, 0.f, 0.f, 0.f, 0.f, 0.f};
  for (int j = j0; j < j1; ++j) {
    int2 e = sedge[j];
    float w = __int_as_float(e.y);
    us8 v = *(const us8*)(h + (size_t)e.x * 1024 + 8 * t);
#pragma unroll
    for (int q = 0; q < 8; ++q) acc[q] += w * bf2f(v[q]);
  }
  if (t == 127) sm0[g] = acc[7];  // time coord (col 1023)
  __syncthreads();
  float m0 = sm0[g];
  if (t == 127) acc[7] = 0.0f;
  float ssl = 0.f;
#pragma unroll
  for (int q = 0; q < 8; ++q) ssl += acc[q] * acc[q];
#pragma unroll
  for (int o = 32; o > 0; o >>= 1) ssl += __shfl_down(ssl, o);
  int lane = threadIdx.x & 63, wv = threadIdx.x >> 6;
  if (lane == 0) s4[wv] = ssl;
  __syncthreads();
  float ss = s4[2 * g] + s4[2 * g + 1];

  float l = ss - m0 * m0;
  float denom = sqrtf(fmaxf(fabsf(l), EPSF));
  float c = sqrtK / denom;
  float xn = fmaxf(c * sqrtf(ss), EPSF);
  float theta = fmaxf(m0 / denom, 1.0f + EPSF);
  float d = sqrtK * acoshf(theta);
  float f = c * (d / xn);
  us8 u;
#pragma unroll
  for (int q = 0; q < 8; ++q) u[q] = f2bf(fmaxf(acc[q], 0.0f) * f);
  if (t == 127) u[7] = 0;  // col 1023 pad
  if (alive) *(us8*)(u16 + (size_t)i * 1024 + 8 * t) = u;
}

// ---------- gather + centroid + logmap + relu + expmap + proj -> y (layer-2 tail) ----------
__global__ __launch_bounds__(256) void gather_centroid_final(
    const unsigned short* __restrict__ h, const int* __restrict__ rs,
    const int2* __restrict__ sedge, float* __restrict__ y, float sqrtKin, float sqrtKout,
    int n) {
  __shared__ float s4[4];
  __shared__ float s4b[4];
  __shared__ float sm0[2];
  int g = threadIdx.x >> 7;
  int t = threadIdx.x & 127;
  int i = blockIdx.x * 2 + g;
  bool alive = (i < n);
  int j0 = alive ? rs[i] : 0, j1 = alive ? rs[i + 1] : 0;
  float acc[8] = {0.f, 0.f, 0.f, 0.f, 0.f, 0.f, 0.f, 0.f};
  for (int j = j0; j < j1; ++j) {
    int2 e = sedge[j];
    float w = __int_as_float(e.y);
    us8 v = *(const us8*)(h + (size_t)e.x * 1024 + 8 * t);
#pragma unroll
    for (int q = 0; q < 8; ++q) acc[q] += w * bf2f(v[q]);
  }
  if (t == 127) sm0[g] = acc[7];
  __syncthreads();
  float m0 = sm0[g];
  if (t == 127) acc[7] = 0.0f;
  float ssl = 0.f;
#pragma unroll
  for (int q = 0; q < 8; ++q) ssl += acc[q] * acc[q];
#pragma unroll
  for (int o = 32; o > 0; o >>= 1) ssl += __shfl_down(ssl, o);
  int lane = threadIdx.x & 63, wv = threadIdx.x >> 6;
  if (lane == 0) s4[wv] = ssl;
  __syncthreads();
  float ss = s4[2 * g] + s4[2 * g + 1];

  float l = ss - m0 * m0;
  float denom = sqrtf(fmaxf(fabsf(l), EPSF));
  float c = sqrtKin / denom;
  float xn = fmaxf(c * sqrtf(ss), EPSF);
  float theta = fmaxf(m0 / denom, 1.0f + EPSF);
  float d = sqrtKin * acoshf(theta);
  float f = c * (d / xn);
  float o_[8];
#pragma unroll
  for (int q = 0; q < 8; ++q) o_[q] = fmaxf(acc[q], 0.0f) * f;
  if (t == 127) o_[7] = 0.0f;
  float ss2l = 0.f;
#pragma unroll
  for (int q = 0; q < 8; ++q) ss2l += o_[q] * o_[q];
#pragma unroll
  for (int o = 32; o > 0; o >>= 1) ss2l += __shfl_down(ss2l, o);
  if (lane == 0) s4b[wv] = ss2l;
  __syncthreads();
  float ss2 = s4b[2 * g] + s4b[2 * g + 1];

  float un = fmaxf(sqrtf(ss2), EPSF);
  float tt = un / sqrtKout;
  float e = expf(tt);
  float ch = 0.5f * (e + 1.0f / e), sh = 0.5f * (e - 1.0f / e);
  float y0 = sqrtKout * ch, sc = sqrtKout * sh / un;
  if (alive) {
    float* yr = y + (size_t)i * 1024;
    int c0 = 8 * t;
#pragma unroll
    for (int q = 0; q < 8; ++q) {
      int col = c0 + q;
      if (col < 1023) yr[1 + col] = sc * o_[q];
    }
    if (t == 0) yr[0] = y0;
  }
}

extern "C" void kernel_launch(void* const* d_in, const int* in_sizes, int n_in,
                              void* d_out, int out_size, void* d_ws, size_t ws_size,
                              hipStream_t stream) {
  const float* x = (const float*)d_in[0];
  const int* es = (const int*)d_in[1];
  const int* ed = (const int*)d_in[2];
  const float* ew = (const float*)d_in[3];
  const float* W1 = (const float*)d_in[4];
  const float* b1 = (const float*)d_in[5];
  const float* W2 = (const float*)d_in[6];
  const float* b2 = (const float*)d_in[7];
  float* y = (float*)d_out;

  const int n = in_sizes[0] / 1024;  // 50000
  const int nE = in_sizes[1];        // 400000
  const int NB = (n + 255) / 256;    // 196
  const int EB = (nE + 255) / 256;

  // workspace layout (offsets 256B-aligned)
  char* ws = (char*)d_ws;
  size_t off = 0;
  auto alloc = [&](size_t bytes) {
    void* p = ws + off;
    off += (bytes + 255) & ~(size_t)255;
    return p;
  };
  unsigned short* u16 = (unsigned short*)alloc((size_t)M_PAD * 1024 * 2);
  unsigned short* w16 = (unsigned short*)alloc((size_t)1024 * 1024 * 2);
  float* mx = (float*)alloc((size_t)M_PAD * 1024 * 4);
  unsigned short* h16 = (unsigned short*)alloc((size_t)M_PAD * 1024 * 2);
  int* cnt = (int*)alloc((size_t)(n + 1) * 4);
  int* excl = (int*)alloc((size_t)n * 4);
  int* rowstart = (int*)alloc((size_t)(n + 1) * 4);
  int* fill = (int*)alloc((size_t)n * 4);
  int* bsum = (int*)alloc(256 * 4);
  int* boff = (int*)alloc(256 * 4);
  int2* sedge = (int2*)alloc((size_t)nE * 8);

  const float sK1 = 1.0f;                 // sqrt(K_IN)
  const float sK2 = 1.0488088481701516f;  // sqrt(1.1)
  const float sK3 = 1.0954451150103321f;  // sqrt(1.2)

  dim3 ggrid(391, 8);
  const int GB = (n + 1) / 2;  // 2 rows per gather block

  // ----- CSR build (edges shared by both layers) -----
  hipMemsetAsync(cnt, 0, (size_t)(n + 1) * 4, stream);
  deg_count<<<EB, 256, 0, stream>>>(ed, cnt, nE);
  scan1<<<NB, 256, 0, stream>>>(cnt, excl, bsum, n);
  scan2<<<1, 256, 0, stream>>>(bsum, boff, NB);
  scan3<<<NB, 256, 0, stream>>>(excl, boff, rowstart, fill, n, nE);
  bucket_fill<<<EB, 256, 0, stream>>>(es, ed, ew, fill, sedge, nE);

  // ----- layer 1 -----
  cvt_rows_bf16<<<n, 256, 0, stream>>>(x, u16);
  cvt_w_bf16<<<1024, 256, 0, stream>>>(W1, w16, 1023, 1024);
  gemm_bt<<<ggrid, 256, 0, stream>>>(u16, w16, b1, mx);
  expmap_to_bf16<<<n, 256, 0, stream>>>(mx, h16, sK1);
  gather_centroid_tangent<<<GB, 256, 0, stream>>>(h16, rowstart, sedge, u16, sK1, n);

  // ----- layer 2 -----
  cvt_w_bf16<<<1024, 256, 0, stream>>>(W2, w16, 1023, 1023);
  gemm_bt<<<ggrid, 256, 0, stream>>>(u16, w16, b2, mx);
  expmap_to_bf16<<<n, 256, 0, stream>>>(mx, h16, sK2);
  gather_centroid_final<<<GB, 256, 0, stream>>>(h16, rowstart, sedge, y, sK2, sK3, n);
}

// Round 4
// 718.583 us; speedup vs baseline: 15.5880x; 1.2229x over previous
//
#include <hip/hip_runtime.h>
#include <math.h>

#define EPSF 1e-7f
#define KPAD 1024
#define M_PAD 50048   // 391 * 128
#define NBM 391
#define NWG (NBM * 8)

typedef __attribute__((ext_vector_type(8))) short bf16x8;
typedef __attribute__((ext_vector_type(4))) float f32x4;
typedef __attribute__((ext_vector_type(4))) unsigned short us4;
typedef __attribute__((ext_vector_type(8))) unsigned short us8;

__device__ inline unsigned short f2bf(float f) {
  unsigned u = __float_as_uint(f);
  return (unsigned short)((u + 0x7FFFu + ((u >> 16) & 1u)) >> 16);
}
__device__ inline float bf2f(unsigned short s) {
  return __uint_as_float(((unsigned)s) << 16);
}

__device__ inline float block_sum256(float v, float* s4) {
#pragma unroll
  for (int o = 32; o > 0; o >>= 1) v += __shfl_down(v, o);
  int lane = threadIdx.x & 63, w = threadIdx.x >> 6;
  __syncthreads();
  if (lane == 0) s4[w] = v;
  __syncthreads();
  return s4[0] + s4[1] + s4[2] + s4[3];
}

__device__ inline void gload_lds16(const void* g, void* l) {
  __builtin_amdgcn_global_load_lds((const __attribute__((address_space(1))) void*)g,
                                   (__attribute__((address_space(3))) void*)l, 16, 0, 0);
}

// ---------- conversions ----------
__global__ __launch_bounds__(256) void cvt_rows_bf16(const float* __restrict__ x,
                                                     unsigned short* __restrict__ o) {
  int i = blockIdx.x, t = threadIdx.x;
  float4 v = *(const float4*)(x + (size_t)i * 1024 + 4 * t);
  us4 u = {f2bf(v.x), f2bf(v.y), f2bf(v.z), f2bf(v.w)};
  *(us4*)(o + (size_t)i * 1024 + 4 * t) = u;
}

__global__ __launch_bounds__(256) void cvt_w_bf16(const float* __restrict__ W,
                                                  unsigned short* __restrict__ o,
                                                  int rows, int cols) {
  int r = blockIdx.x, t = threadIdx.x;
  int c0 = 4 * t;
  us4 u;
#pragma unroll
  for (int j = 0; j < 4; ++j) {
    int c = c0 + j;
    float v = (r < rows && c < cols) ? W[(size_t)r * cols + c] : 0.0f;
    u[j] = f2bf(v);
  }
  *(us4*)(o + (size_t)r * 1024 + c0) = u;
}

// ---------- GEMM: C[i][j] = bf16(sum_k A16[i][k] * B16[j][k] + bias[j]) ----------
// BK=64 (2x32 chunks per barrier), XCD-chunked block swizzle, bf16 output.
__global__ __launch_bounds__(256) void gemm_bt(const unsigned short* __restrict__ A,
                                               const unsigned short* __restrict__ B,
                                               const float* __restrict__ bias,
                                               unsigned short* __restrict__ C) {
  __shared__ unsigned short lA[2][128 * 32];
  __shared__ unsigned short lB[2][128 * 32];
  const int wg = blockIdx.x;
  const int swz = (wg & 7) * NBM + (wg >> 3);  // bijective: 3128 = 8*391
  const int bm = swz >> 3, bn = swz & 7;
  const int tid = threadIdx.x;
  const int wave = tid >> 6, lane = tid & 63;
  const int wr = wave >> 1, wc = wave & 1;
  const int fr = lane & 15, fg = lane >> 4;

  f32x4 acc[4][4];
#pragma unroll
  for (int m = 0; m < 4; ++m)
#pragma unroll
    for (int n2 = 0; n2 < 4; ++n2) acc[m][n2] = (f32x4)0.0f;

  for (int k0 = 0; k0 < KPAD; k0 += 64) {
#pragma unroll
    for (int h = 0; h < 2; ++h) {
#pragma unroll
      for (int q = 0; q < 2; ++q) {
        int row = q * 64 + wave * 16 + (lane >> 2);
        int kk = ((lane & 3) ^ ((row >> 1) & 3)) << 3;
        gload_lds16(A + (size_t)(bm * 128 + row) * KPAD + k0 + h * 32 + kk,
                    &lA[h][row * 32 + ((lane & 3) << 3)]);
        gload_lds16(B + (size_t)(bn * 128 + row) * KPAD + k0 + h * 32 + kk,
                    &lB[h][row * 32 + ((lane & 3) << 3)]);
      }
    }
    __syncthreads();
#pragma unroll
    for (int h = 0; h < 2; ++h) {
      bf16x8 a[4], b[4];
#pragma unroll
      for (int m = 0; m < 4; ++m) {
        int row = wr * 64 + m * 16 + fr;
        a[m] = *(const bf16x8*)&lA[h][row * 32 + ((fg ^ ((row >> 1) & 3)) << 3)];
      }
#pragma unroll
      for (int n2 = 0; n2 < 4; ++n2) {
        int row = wc * 64 + n2 * 16 + fr;
        b[n2] = *(const bf16x8*)&lB[h][row * 32 + ((fg ^ ((row >> 1) & 3)) << 3)];
      }
#pragma unroll
      for (int m = 0; m < 4; ++m)
#pragma unroll
        for (int n2 = 0; n2 < 4; ++n2)
          acc[m][n2] = __builtin_amdgcn_mfma_f32_16x16x32_bf16(a[m], b[n2], acc[m][n2], 0, 0, 0);
    }
    __syncthreads();
  }

  const int crow0 = bm * 128 + wr * 64;
  const int ccol0 = bn * 128 + wc * 64;
#pragma unroll
  for (int m = 0; m < 4; ++m) {
#pragma unroll
    for (int n2 = 0; n2 < 4; ++n2) {
      int col = ccol0 + n2 * 16 + fr;
      float bv = (col < 1023) ? bias[col] : 0.0f;
      int row0 = crow0 + m * 16 + fg * 4;
      unsigned short* cp = C + (size_t)row0 * 1024 + col;
#pragma unroll
      for (int j = 0; j < 4; ++j) cp[(size_t)j * 1024] = f2bf(acc[m][n2][j] + bv);
    }
  }
}

// ---------- per-row expmap scale: sc table + patch raw[1023] = h0/sc ----------
__global__ __launch_bounds__(256) void row_scale(unsigned short* __restrict__ raw,
                                                 float* __restrict__ sc_tab, float sqrtK) {
  __shared__ float s4[4];
  int i = blockIdx.x, t = threadIdx.x;
  const us4 v = *(const us4*)(raw + (size_t)i * 1024 + 4 * t);
  float f0 = bf2f(v[0]), f1 = bf2f(v[1]), f2 = bf2f(v[2]), f3 = bf2f(v[3]);
  if (t == 255) f3 = 0.0f;  // col 1023 pad
  float ss = block_sum256(f0 * f0 + f1 * f1 + f2 * f2 + f3 * f3, s4);
  float un = fmaxf(sqrtf(ss), EPSF);
  float tt = un / sqrtK;
  float e = expf(tt);
  float ch = 0.5f * (e + 1.0f / e), sh = 0.5f * (e - 1.0f / e);
  float h0 = sqrtK * ch, sc = sqrtK * sh / un;
  if (t == 0) sc_tab[i] = sc;
  if (t == 255) raw[(size_t)i * 1024 + 1023] = f2bf(h0 / sc);
}

// ---------- CSR build ----------
__global__ __launch_bounds__(256) void deg_count(const int* __restrict__ ed, int* __restrict__ cnt,
                                                 int nE) {
  int i = blockIdx.x * 256 + threadIdx.x;
  if (i < nE) atomicAdd(&cnt[ed[i]], 1);
}

__global__ __launch_bounds__(256) void scan1(const int* __restrict__ cnt, int* __restrict__ excl,
                                             int* __restrict__ bsum, int n) {
  __shared__ int s[256];
  int t = threadIdx.x;
  int i = blockIdx.x * 256 + t;
  int v = (i < n) ? cnt[i] : 0;
  s[t] = v;
  __syncthreads();
#pragma unroll
  for (int o = 1; o < 256; o <<= 1) {
    int add = (t >= o) ? s[t - o] : 0;
    __syncthreads();
    s[t] += add;
    __syncthreads();
  }
  if (i < n) excl[i] = s[t] - v;
  if (t == 255) bsum[blockIdx.x] = s[t];
}

__global__ __launch_bounds__(256) void scan2(int* __restrict__ bsum, int* __restrict__ boff,
                                             int nb) {
  __shared__ int s[256];
  int t = threadIdx.x;
  int v = (t < nb) ? bsum[t] : 0;
  s[t] = v;
  __syncthreads();
#pragma unroll
  for (int o = 1; o < 256; o <<= 1) {
    int add = (t >= o) ? s[t - o] : 0;
    __syncthreads();
    s[t] += add;
    __syncthreads();
  }
  if (t < nb) boff[t] = s[t] - v;
}

__global__ __launch_bounds__(256) void scan3(int* __restrict__ excl, const int* __restrict__ boff,
                                             int* __restrict__ rowstart, int* __restrict__ fill,
                                             int n, int nE) {
  int i = blockIdx.x * 256 + threadIdx.x;
  if (i < n) {
    int v = excl[i] + boff[blockIdx.x];
    rowstart[i] = v;
    fill[i] = v;
  }
  if (i == 0) rowstart[n] = nE;
}

__global__ __launch_bounds__(256) void bucket_fill(const int* __restrict__ es,
                                                   const int* __restrict__ ed,
                                                   const float* __restrict__ ew,
                                                   int* __restrict__ fill,
                                                   int2* __restrict__ sedge, int nE) {
  int i = blockIdx.x * 256 + threadIdx.x;
  if (i < nE) {
    int d = ed[i];
    int pos = atomicAdd(&fill[d], 1);
    sedge[pos] = make_int2(es[i], __float_as_int(ew[i]));
  }
}

// ---------- gather core: acc[8] += (ew*sc[src]) * raw[src][8t..8t+7], 4-deep MLP ----------
__device__ inline void gather_row(const unsigned short* __restrict__ h,
                                  const float* __restrict__ sc,
                                  const int2* __restrict__ sedge, int j0, int j1, int t,
                                  float* acc) {
  int j = j0;
  for (; j + 4 <= j1; j += 4) {
    int2 e0 = sedge[j], e1 = sedge[j + 1], e2 = sedge[j + 2], e3 = sedge[j + 3];
    float w0 = __int_as_float(e0.y) * sc[e0.x];
    float w1 = __int_as_float(e1.y) * sc[e1.x];
    float w2 = __int_as_float(e2.y) * sc[e2.x];
    float w3 = __int_as_float(e3.y) * sc[e3.x];
    us8 v0 = *(const us8*)(h + (size_t)e0.x * 1024 + 8 * t);
    us8 v1 = *(const us8*)(h + (size_t)e1.x * 1024 + 8 * t);
    us8 v2 = *(const us8*)(h + (size_t)e2.x * 1024 + 8 * t);
    us8 v3 = *(const us8*)(h + (size_t)e3.x * 1024 + 8 * t);
#pragma unroll
    for (int q = 0; q < 8; ++q) {
      acc[q] += w0 * bf2f(v0[q]);
      acc[q] += w1 * bf2f(v1[q]);
      acc[q] += w2 * bf2f(v2[q]);
      acc[q] += w3 * bf2f(v3[q]);
    }
  }
  for (; j < j1; ++j) {
    int2 e = sedge[j];
    float w = __int_as_float(e.y) * sc[e.x];
    us8 v = *(const us8*)(h + (size_t)e.x * 1024 + 8 * t);
#pragma unroll
    for (int q = 0; q < 8; ++q) acc[q] += w * bf2f(v[q]);
  }
}

// ---------- gather + centroid + logmap0 + relu -> bf16 tangent (layer-1 tail) ----------
__global__ __launch_bounds__(256) void gather_centroid_tangent(
    const unsigned short* __restrict__ h, const float* __restrict__ sc,
    const int* __restrict__ rs, const int2* __restrict__ sedge,
    unsigned short* __restrict__ u16, float sqrtK, int n) {
  __shared__ float s4[4];
  __shared__ float sm0[2];
  int g = threadIdx.x >> 7;   // sub-block 0/1
  int t = threadIdx.x & 127;  // 0..127
  int i = blockIdx.x * 2 + g;
  bool alive = (i < n);
  int j0 = alive ? rs[i] : 0, j1 = alive ? rs[i + 1] : 0;
  float acc[8] = {0.f, 0.f, 0.f, 0.f, 0.f, 0.f, 0.f, 0.f};
  gather_row(h, sc, sedge, j0, j1, t, acc);
  if (t == 127) sm0[g] = acc[7];  // time coord (col 1023)
  __syncthreads();
  float m0 = sm0[g];
  if (t == 127) acc[7] = 0.0f;
  float ssl = 0.f;
#pragma unroll
  for (int q = 0; q < 8; ++q) ssl += acc[q] * acc[q];
#pragma unroll
  for (int o = 32; o > 0; o >>= 1) ssl += __shfl_down(ssl, o);
  int lane = threadIdx.x & 63, wv = threadIdx.x >> 6;
  if (lane == 0) s4[wv] = ssl;
  __syncthreads();
  float ss = s4[2 * g] + s4[2 * g + 1];

  float l = ss - m0 * m0;
  float denom = sqrtf(fmaxf(fabsf(l), EPSF));
  float c = sqrtK / denom;
  float xn = fmaxf(c * sqrtf(ss), EPSF);
  float theta = fmaxf(m0 / denom, 1.0f + EPSF);
  float d = sqrtK * acoshf(theta);
  float f = c * (d / xn);
  us8 u;
#pragma unroll
  for (int q = 0; q < 8; ++q) u[q] = f2bf(fmaxf(acc[q], 0.0f) * f);
  if (t == 127) u[7] = 0;  // col 1023 pad
  if (alive) *(us8*)(u16 + (size_t)i * 1024 + 8 * t) = u;
}

// ---------- gather + centroid + logmap + relu + expmap + proj -> y (layer-2 tail) ----------
__global__ __launch_bounds__(256) void gather_centroid_final(
    const unsigned short* __restrict__ h, const float* __restrict__ sc,
    const int* __restrict__ rs, const int2* __restrict__ sedge, float* __restrict__ y,
    float sqrtKin, float sqrtKout, int n) {
  __shared__ float s4[4];
  __shared__ float s4b[4];
  __shared__ float sm0[2];
  int g = threadIdx.x >> 7;
  int t = threadIdx.x & 127;
  int i = blockIdx.x * 2 + g;
  bool alive = (i < n);
  int j0 = alive ? rs[i] : 0, j1 = alive ? rs[i + 1] : 0;
  float acc[8] = {0.f, 0.f, 0.f, 0.f, 0.f, 0.f, 0.f, 0.f};
  gather_row(h, sc, sedge, j0, j1, t, acc);
  if (t == 127) sm0[g] = acc[7];
  __syncthreads();
  float m0 = sm0[g];
  if (t == 127) acc[7] = 0.0f;
  float ssl = 0.f;
#pragma unroll
  for (int q = 0; q < 8; ++q) ssl += acc[q] * acc[q];
#pragma unroll
  for (int o = 32; o > 0; o >>= 1) ssl += __shfl_down(ssl, o);
  int lane = threadIdx.x & 63, wv = threadIdx.x >> 6;
  if (lane == 0) s4[wv] = ssl;
  __syncthreads();
  float ss = s4[2 * g] + s4[2 * g + 1];

  float l = ss - m0 * m0;
  float denom = sqrtf(fmaxf(fabsf(l), EPSF));
  float c = sqrtKin / denom;
  float xn = fmaxf(c * sqrtf(ss), EPSF);
  float theta = fmaxf(m0 / denom, 1.0f + EPSF);
  float d = sqrtKin * acoshf(theta);
  float f = c * (d / xn);
  float o_[8];
#pragma unroll
  for (int q = 0; q < 8; ++q) o_[q] = fmaxf(acc[q], 0.0f) * f;
  if (t == 127) o_[7] = 0.0f;
  float ss2l = 0.f;
#pragma unroll
  for (int q = 0; q < 8; ++q) ss2l += o_[q] * o_[q];
#pragma unroll
  for (int o = 32; o > 0; o >>= 1) ss2l += __shfl_down(ss2l, o);
  if (lane == 0) s4b[wv] = ss2l;
  __syncthreads();
  float ss2 = s4b[2 * g] + s4b[2 * g + 1];

  float un = fmaxf(sqrtf(ss2), EPSF);
  float tt = un / sqrtKout;
  float e = expf(tt);
  float ch = 0.5f * (e + 1.0f / e), sh = 0.5f * (e - 1.0f / e);
  float y0 = sqrtKout * ch, scale = sqrtKout * sh / un;
  if (alive) {
    float* yr = y + (size_t)i * 1024;
    int c0 = 8 * t;
#pragma unroll
    for (int q = 0; q < 8; ++q) {
      int col = c0 + q;
      if (col < 1023) yr[1 + col] = scale * o_[q];
    }
    if (t == 0) yr[0] = y0;
  }
}

extern "C" void kernel_launch(void* const* d_in, const int* in_sizes, int n_in,
                              void* d_out, int out_size, void* d_ws, size_t ws_size,
                              hipStream_t stream) {
  const float* x = (const float*)d_in[0];
  const int* es = (const int*)d_in[1];
  const int* ed = (const int*)d_in[2];
  const float* ew = (const float*)d_in[3];
  const float* W1 = (const float*)d_in[4];
  const float* b1 = (const float*)d_in[5];
  const float* W2 = (const float*)d_in[6];
  const float* b2 = (const float*)d_in[7];
  float* y = (float*)d_out;

  const int n = in_sizes[0] / 1024;  // 50000
  const int nE = in_sizes[1];        // 400000
  const int NB = (n + 255) / 256;    // 196
  const int EB = (nE + 255) / 256;

  // workspace layout (offsets 256B-aligned)
  char* ws = (char*)d_ws;
  size_t off = 0;
  auto alloc = [&](size_t bytes) {
    void* p = ws + off;
    off += (bytes + 255) & ~(size_t)255;
    return p;
  };
  unsigned short* u16 = (unsigned short*)alloc((size_t)M_PAD * 1024 * 2);
  unsigned short* w16 = (unsigned short*)alloc((size_t)1024 * 1024 * 2);
  unsigned short* raw16 = (unsigned short*)alloc((size_t)M_PAD * 1024 * 2);
  float* sc_tab = (float*)alloc((size_t)M_PAD * 4);
  int* cnt = (int*)alloc((size_t)(n + 1) * 4);
  int* excl = (int*)alloc((size_t)n * 4);
  int* rowstart = (int*)alloc((size_t)(n + 1) * 4);
  int* fill = (int*)alloc((size_t)n * 4);
  int* bsum = (int*)alloc(256 * 4);
  int* boff = (int*)alloc(256 * 4);
  int2* sedge = (int2*)alloc((size_t)nE * 8);

  const float sK1 = 1.0f;                 // sqrt(K_IN)
  const float sK2 = 1.0488088481701516f;  // sqrt(1.1)
  const float sK3 = 1.0954451150103321f;  // sqrt(1.2)

  const int GB = (n + 1) / 2;  // 2 rows per gather block

  // ----- CSR build (edges shared by both layers) -----
  hipMemsetAsync(cnt, 0, (size_t)(n + 1) * 4, stream);
  deg_count<<<EB, 256, 0, stream>>>(ed, cnt, nE);
  scan1<<<NB, 256, 0, stream>>>(cnt, excl, bsum, n);
  scan2<<<1, 256, 0, stream>>>(bsum, boff, NB);
  scan3<<<NB, 256, 0, stream>>>(excl, boff, rowstart, fill, n, nE);
  bucket_fill<<<EB, 256, 0, stream>>>(es, ed, ew, fill, sedge, nE);

  // ----- layer 1 -----
  cvt_rows_bf16<<<n, 256, 0, stream>>>(x, u16);
  cvt_w_bf16<<<1024, 256, 0, stream>>>(W1, w16, 1023, 1024);
  gemm_bt<<<NWG, 256, 0, stream>>>(u16, w16, b1, raw16);
  row_scale<<<n, 256, 0, stream>>>(raw16, sc_tab, sK1);
  gather_centroid_tangent<<<GB, 256, 0, stream>>>(raw16, sc_tab, rowstart, sedge, u16, sK1, n);

  // ----- layer 2 -----
  cvt_w_bf16<<<1024, 256, 0, stream>>>(W2, w16, 1023, 1023);
  gemm_bt<<<NWG, 256, 0, stream>>>(u16, w16, b2, raw16);
  row_scale<<<n, 256, 0, stream>>>(raw16, sc_tab, sK2);
  gather_centroid_final<<<GB, 256, 0, stream>>>(raw16, sc_tab, rowstart, sedge, y, sK2, sK3, n);
}